// Round 3
// baseline (434.416 us; speedup 1.0000x reference)
//
#include <hip/hip_runtime.h>
#include <hip/hip_bf16.h>

#define N_TOK 131072
#define DIM   512
#define HID   512
#define NEXP  10

using bf16x8 = __attribute__((ext_vector_type(8))) short;
using f32x4  = __attribute__((ext_vector_type(4))) float;

__device__ __forceinline__ short f2bf(float f) {
    union { float f; unsigned u; } v; v.f = f;
    unsigned u = v.u;
    return (short)((u + 0x7FFFu + ((u >> 16) & 1u)) >> 16);   // RNE
}

#define GLOAD16(g, l) __builtin_amdgcn_global_load_lds( \
    (const __attribute__((address_space(1))) void*)(g),  \
    (__attribute__((address_space(3))) void*)(l), 16, 0, 0)

// ---------------- router: logits = x @ Wr^T + br, argmax ----------------
__global__ __launch_bounds__(256) void router_kernel(
    const float* __restrict__ x, const float* __restrict__ Wr,
    const float* __restrict__ br, int* __restrict__ eid,
    float* __restrict__ ids_out, int* __restrict__ counts)
{
    __shared__ float wr[NEXP][DIM];
    __shared__ int lcnt[NEXP];
    int tid = threadIdx.x;
    for (int i = tid; i < NEXP * DIM / 4; i += 256)
        ((float4*)wr)[i] = ((const float4*)Wr)[i];
    if (tid < NEXP) lcnt[tid] = 0;
    __syncthreads();

    int lane  = tid & 63;
    int wave  = tid >> 6;
    int gwave = blockIdx.x * 4 + wave;
    int nwav  = gridDim.x * 4;

    for (int t = gwave; t < N_TOK; t += nwav) {
        const float4* xr = (const float4*)(x + (size_t)t * DIM);
        float4 v0 = xr[lane * 2], v1 = xr[lane * 2 + 1];
        float xf[8] = {v0.x, v0.y, v0.z, v0.w, v1.x, v1.y, v1.z, v1.w};
        float dot[NEXP];
        #pragma unroll
        for (int e = 0; e < NEXP; ++e) {
            const float* wv = &wr[e][lane * 8];
            float s = 0.f;
            #pragma unroll
            for (int j = 0; j < 8; ++j) s = fmaf(xf[j], wv[j], s);
            dot[e] = s;
        }
        #pragma unroll
        for (int off = 32; off > 0; off >>= 1) {
            #pragma unroll
            for (int e = 0; e < NEXP; ++e) dot[e] += __shfl_xor(dot[e], off, 64);
        }
        if (lane == 0) {
            int best = 0; float bv = dot[0] + br[0];
            #pragma unroll
            for (int e = 1; e < NEXP; ++e) {
                float v = dot[e] + br[e];
                if (v > bv) { bv = v; best = e; }
            }
            eid[t] = best;
            ids_out[t] = (float)best;
            atomicAdd(&lcnt[best], 1);
        }
    }
    __syncthreads();
    if (tid < NEXP) atomicAdd(&counts[tid], lcnt[tid]);
}

// ---------------- prefix sums: token offsets + tile offsets (128-row tiles) ----------------
__global__ void offsets_kernel(const int* __restrict__ counts,
                               int* __restrict__ offsets, int* __restrict__ toff)
{
    if (threadIdx.x == 0) {
        int acc = 0, ta = 0;
        for (int e = 0; e < NEXP; ++e) {
            offsets[e] = acc; toff[e] = ta;
            acc += counts[e]; ta += (counts[e] + 127) >> 7;
        }
        offsets[NEXP] = acc; toff[NEXP] = ta;
    }
}

// ---------------- bucket scatter: perm[offset[e] + pos] = token ----------------
__global__ __launch_bounds__(256) void scatter_kernel(
    const int* __restrict__ eid, const int* __restrict__ offsets,
    int* __restrict__ cursors, int* __restrict__ perm)
{
    __shared__ int lcnt[NEXP], lbase[NEXP];
    int tid = threadIdx.x;
    if (tid < NEXP) lcnt[tid] = 0;
    __syncthreads();
    int t = blockIdx.x * 256 + tid;
    int e = 0, lpos = 0;
    if (t < N_TOK) {
        e = eid[t];
        lpos = atomicAdd(&lcnt[e], 1);
    }
    __syncthreads();
    if (tid < NEXP) lbase[tid] = atomicAdd(&cursors[tid], lcnt[tid]);
    __syncthreads();
    if (t < N_TOK) perm[offsets[e] + lbase[e] + lpos] = t;
}

// ---------------- transpose-convert weights: [512][512] f32 -> [n][k] bf16 ----------------
__global__ __launch_bounds__(256) void wconvert_kernel(
    const float* __restrict__ W1, const float* __restrict__ W2,
    short* __restrict__ W1bT, short* __restrict__ W2bT)
{
    int mat = blockIdx.z;
    const float* src = (mat < NEXP) ? W1 + (size_t)mat * 512 * 512
                                    : W2 + (size_t)(mat - NEXP) * 512 * 512;
    short* dst = (mat < NEXP) ? W1bT + (size_t)mat * 512 * 512
                              : W2bT + (size_t)(mat - NEXP) * 512 * 512;
    __shared__ float tile[64][65];
    int r0 = blockIdx.y * 64, c0 = blockIdx.x * 64;
    int tid = threadIdx.x;
    int tr = tid >> 4, tc4 = (tid & 15) * 4;
    #pragma unroll
    for (int i = 0; i < 4; ++i) {
        float4 v = *(const float4*)(src + (size_t)(r0 + i * 16 + tr) * 512 + c0 + tc4);
        tile[i * 16 + tr][tc4 + 0] = v.x; tile[i * 16 + tr][tc4 + 1] = v.y;
        tile[i * 16 + tr][tc4 + 2] = v.z; tile[i * 16 + tr][tc4 + 3] = v.w;
    }
    __syncthreads();
    #pragma unroll
    for (int i = 0; i < 4; ++i) {
        int cc = i * 16 + tr;           // output row (= source col)
        ushort4 o;
        o.x = (ushort)f2bf(tile[tc4 + 0][cc]); o.y = (ushort)f2bf(tile[tc4 + 1][cc]);
        o.z = (ushort)f2bf(tile[tc4 + 2][cc]); o.w = (ushort)f2bf(tile[tc4 + 3][cc]);
        *(ushort4*)(dst + (size_t)(c0 + cc) * 512 + r0 + tc4) = o;
    }
}

// ---------------- MFMA expert GEMM: 128 rows x 256 cols tile, K=512, 8 waves ----------------
// LAYER==1: A = gathered x rows (fp32 -> bf16 reg-stage), out = relu(.+b1) -> h (bf16)
// LAYER==2: A = packed h rows (bf16 via global_load_lds), out = . + b2 -> out[tok] (f32)
template<int LAYER>
__global__ __launch_bounds__(512, 4) void expert_gemm(
    const float* __restrict__ x, const short* __restrict__ hA,
    const short* __restrict__ WT, const float* __restrict__ bias,
    const int* __restrict__ offsets, const int* __restrict__ toff,
    const int* __restrict__ perm,
    short* __restrict__ hOut, float* __restrict__ out)
{
    int g = blockIdx.x;
    if (g >= toff[NEXP]) return;
    int e = 0;
    #pragma unroll
    for (int k = 1; k < NEXP; ++k) e += (g >= toff[k]);
    int beg = offsets[e], cnt = offsets[e + 1] - beg;
    int m0 = (g - toff[e]) * 128;
    int nb = blockIdx.y * 256;          // column-tile base

    __shared__ int toks[128];
    __shared__ short Abuf[2][128 * 32];   // [row][k] bf16, 8 KB each
    __shared__ short Bbuf[2][256 * 32];   // [n][k]   bf16, 16 KB each

    int tid = threadIdx.x, lane = tid & 63, w = tid >> 6;
    if (tid < 128) toks[tid] = perm[beg + min(m0 + tid, cnt - 1)];
    __syncthreads();

    // staging assignments: A = 512 chunks of 16B (1/thread); B = 1024 chunks (2/thread)
    int arow = tid >> 2;                 // 0..127
    int kq   = tid & 3;                  // 16B quarter of the 64B k-row
    const float* xr   = nullptr;
    const short* ha   = nullptr;
    if (LAYER == 1) xr = x + (size_t)toks[arow] * DIM + kq * 8;
    else            ha = hA + (size_t)(beg + min(m0 + arow, cnt - 1)) * HID + kq * 8;
    const short* bp = WT + (size_t)e * 512 * 512 + (size_t)(nb + (tid >> 2)) * 512 + kq * 8;

    auto stage = [&](int t, int b) {
        char* bl = (char*)&Bbuf[b][0] + w * 1024;
        GLOAD16(bp + t * 32,         bl);
        GLOAD16(bp + t * 32 + 65536, bl + 8192);   // +128 n-rows
        if (LAYER == 1) {
            float4 a0 = *(const float4*)(xr + t * 32);
            float4 a1 = *(const float4*)(xr + t * 32 + 4);
            bf16x8 p;
            p[0] = f2bf(a0.x); p[1] = f2bf(a0.y); p[2] = f2bf(a0.z); p[3] = f2bf(a0.w);
            p[4] = f2bf(a1.x); p[5] = f2bf(a1.y); p[6] = f2bf(a1.z); p[7] = f2bf(a1.w);
            *(bf16x8*)((char*)&Abuf[b][0] + tid * 16) = p;
        } else {
            GLOAD16(ha + t * 32, (char*)&Abuf[b][0] + w * 1024);
        }
    };

    f32x4 acc[4][4];
    #pragma unroll
    for (int i = 0; i < 4; ++i)
        #pragma unroll
        for (int j = 0; j < 4; ++j) acc[i][j] = (f32x4){0.f, 0.f, 0.f, 0.f};

    int wr = w >> 2, wc = w & 3;         // 2 x 4 wave grid, 64x64 per wave
    int lrow = lane & 15;
    int lk   = (lane >> 4) * 8;          // k offset in shorts

    auto compute = [&](int b) {
        const short* A = &Abuf[b][0];
        const short* B = &Bbuf[b][0];
        bf16x8 af[4], bfv[4];
        #pragma unroll
        for (int i = 0; i < 4; ++i)
            af[i] = *(const bf16x8*)(A + (wr * 64 + i * 16 + lrow) * 32 + lk);
        #pragma unroll
        for (int j = 0; j < 4; ++j)
            bfv[j] = *(const bf16x8*)(B + (wc * 64 + j * 16 + lrow) * 32 + lk);
        #pragma unroll
        for (int i = 0; i < 4; ++i)
            #pragma unroll
            for (int j = 0; j < 4; ++j)
                acc[i][j] = __builtin_amdgcn_mfma_f32_16x16x32_bf16(af[i], bfv[j], acc[i][j], 0, 0, 0);
    };

    stage(0, 0);
    __syncthreads();
    #pragma unroll 1
    for (int t = 0; t < 14; t += 2) {
        stage(t + 1, 1); compute(0); __syncthreads();
        stage(t + 2, 0); compute(1); __syncthreads();
    }
    stage(15, 1); compute(0); __syncthreads();
    compute(1);

    // ---- epilogue ----
    const float* be = bias + (size_t)e * 512;
    int colb = nb + wc * 64 + lrow;
    float bv[4];
    #pragma unroll
    for (int j = 0; j < 4; ++j) bv[j] = be[colb + j * 16];

    #pragma unroll
    for (int i = 0; i < 4; ++i) {
        #pragma unroll
        for (int q = 0; q < 4; ++q) {
            int rr = wr * 64 + i * 16 + ((lane >> 4) << 2) + q;
            if (m0 + rr < cnt) {
                if (LAYER == 1) {
                    short* hp = hOut + (size_t)(beg + m0 + rr) * HID + colb;
                    #pragma unroll
                    for (int j = 0; j < 4; ++j) {
                        float v = acc[i][j][q] + bv[j];
                        hp[j * 16] = f2bf(v > 0.f ? v : 0.f);
                    }
                } else {
                    float* op = out + (size_t)toks[rr] * HID + colb;
                    #pragma unroll
                    for (int j = 0; j < 4; ++j)
                        op[j * 16] = acc[i][j][q] + bv[j];
                }
            }
        }
    }
}

extern "C" void kernel_launch(void* const* d_in, const int* in_sizes, int n_in,
                              void* d_out, int out_size, void* d_ws, size_t ws_size,
                              hipStream_t stream)
{
    const float* x  = (const float*)d_in[0];
    const float* Wr = (const float*)d_in[1];
    const float* br = (const float*)d_in[2];
    const float* W1 = (const float*)d_in[3];
    const float* b1 = (const float*)d_in[4];
    const float* W2 = (const float*)d_in[5];
    const float* b2 = (const float*)d_in[6];

    float* out     = (float*)d_out;
    float* ids_out = out + (size_t)N_TOK * HID;

    char* ws     = (char*)d_ws;
    int* counts  = (int*)ws;            // 16 ints
    int* offsets = counts + 16;         // 11 used
    int* toff    = counts + 32;         // 11 used
    int* cursors = counts + 48;         // 16
    int* eid     = (int*)(ws + 1024);
    int* perm    = eid + N_TOK;
    short* W1bT  = (short*)(ws + 1024 + (size_t)2 * N_TOK * 4);
    short* W2bT  = W1bT + (size_t)NEXP * 512 * 512;
    short* h     = W2bT + (size_t)NEXP * 512 * 512;

    hipMemsetAsync(d_ws, 0, 1024, stream);
    router_kernel<<<2048, 256, 0, stream>>>(x, Wr, br, eid, ids_out, counts);
    wconvert_kernel<<<dim3(8, 8, 2 * NEXP), 256, 0, stream>>>(W1, W2, W1bT, W2bT);
    offsets_kernel<<<1, 64, 0, stream>>>(counts, offsets, toff);
    scatter_kernel<<<512, 256, 0, stream>>>(eid, offsets, cursors, perm);

    int ntiles = (N_TOK + 127) / 128 + NEXP;   // upper bound on row-tiles
    expert_gemm<1><<<dim3(ntiles, 2), 512, 0, stream>>>(x, nullptr, W1bT, b1, offsets, toff, perm, h, nullptr);
    expert_gemm<2><<<dim3(ntiles, 2), 512, 0, stream>>>(nullptr, h, W2bT, b2, offsets, toff, perm, nullptr, out);
}